// Round 4
// baseline (3050.194 us; speedup 1.0000x reference)
//
#include <hip/hip_runtime.h>
#include <hip/hip_bf16.h>

// Problem constants (fixed by the reference)
constexpr int B_  = 4;
constexpr int N_  = 2048;
constexpr int HID_ = 1024;
constexpr int NH_ = 4;
constexpr int DK_ = 256;
constexpr int DV_ = 512;
constexpr int C_  = 64;     // chunk size
constexpr int NC_ = 32;     // chunks per sequence
constexpr int M_  = B_ * N_;  // 8192 rows

// ---------------------------------------------------------------------------
// Generic fp32 tiled GEMM: Out[M,N] = X[M,K] @ W[K,N].  64x64 tile, BK=16,
// 256 threads, 4x4 per thread.
// ---------------------------------------------------------------------------
template<bool BF16OUT>
__global__ __launch_bounds__(256) void gemm_f32(const float* __restrict__ X,
    const float* __restrict__ W, void* __restrict__ OutV, int N, int K) {
  __shared__ float As[16][68];   // As[kk][row]
  __shared__ float Bs[16][68];   // Bs[kk][col]
  const int tid  = threadIdx.x;
  const int brow = blockIdx.y * 64;
  const int bcol = blockIdx.x * 64;
  const int tx = tid & 15, ty = tid >> 4;      // 16x16 thread grid
  const int arow = tid >> 2;                   // 0..63
  const int ac4  = (tid & 3) * 4;              // 0,4,8,12
  const int bkrow = tid >> 4;                  // 0..15
  const int bc4   = (tid & 15) * 4;            // 0..60

  float acc[4][4] = {};

  for (int k0 = 0; k0 < K; k0 += 16) {
    float4 av = *(const float4*)(X + (size_t)(brow + arow) * K + k0 + ac4);
    float4 bv = *(const float4*)(W + (size_t)(k0 + bkrow) * N + bcol + bc4);
    As[ac4 + 0][arow] = av.x;
    As[ac4 + 1][arow] = av.y;
    As[ac4 + 2][arow] = av.z;
    As[ac4 + 3][arow] = av.w;
    *(float4*)&Bs[bkrow][bc4] = bv;
    __syncthreads();
#pragma unroll
    for (int kk = 0; kk < 16; ++kk) {
      float ar[4], br[4];
      *(float4*)ar = *(const float4*)&As[kk][ty * 4];
      *(float4*)br = *(const float4*)&Bs[kk][tx * 4];
#pragma unroll
      for (int i = 0; i < 4; ++i)
#pragma unroll
        for (int j = 0; j < 4; ++j)
          acc[i][j] += ar[i] * br[j];
    }
    __syncthreads();
  }

  if constexpr (BF16OUT) {
    __hip_bfloat16* Out = (__hip_bfloat16*)OutV;
#pragma unroll
    for (int i = 0; i < 4; ++i)
#pragma unroll
      for (int j = 0; j < 4; ++j)
        Out[(size_t)(brow + ty * 4 + i) * N + bcol + tx * 4 + j] =
            __float2bfloat16(acc[i][j]);
  } else {
    float* Out = (float*)OutV;
#pragma unroll
    for (int i = 0; i < 4; ++i)
#pragma unroll
      for (int j = 0; j < 4; ++j)
        Out[(size_t)(brow + ty * 4 + i) * N + bcol + tx * 4 + j] = acc[i][j];
  }
}

// ---------------------------------------------------------------------------
// gk[b,h,n] = logsigmoid(x[b,n,:]·Wgk[:,h] + bgk[h]) / 16
// one block (256 thr) per (b,n); 64-thread group w handles head w.
// ---------------------------------------------------------------------------
__global__ __launch_bounds__(256) void gk_kernel(const float* __restrict__ x,
    const float* __restrict__ Wgk, const float* __restrict__ bgk,
    float* __restrict__ gkbuf) {
  const int row  = blockIdx.x;         // b*N + n
  const int b    = row / N_;
  const int n    = row - b * N_;
  const int tid  = threadIdx.x;
  const int wv   = tid >> 6;           // head
  const int ln   = tid & 63;
  __shared__ float red2[256];
  const float* xr = x + (size_t)row * HID_;
  float s = 0.f;
  for (int i = ln; i < HID_; i += 64) s += xr[i] * Wgk[i * NH_ + wv];
  red2[tid] = s;
  __syncthreads();
  for (int off = 32; off; off >>= 1) {
    if (ln < off) red2[tid] += red2[tid + off];
    __syncthreads();
  }
  if (ln == 0) {
    float z  = red2[wv * 64] + bgk[wv];
    float ls = fminf(z, 0.f) - log1pf(expf(-fabsf(z)));
    gkbuf[((size_t)(b * NH_ + wv)) * N_ + n] = ls * (1.0f / 16.0f);
  }
}

// ---------------------------------------------------------------------------
// per-(bh,chunk) inclusive cumsum of gk: one thread per chunk, serial.
// ---------------------------------------------------------------------------
__global__ __launch_bounds__(64) void cumsum_kernel(const float* __restrict__ gkbuf,
                                                    float* __restrict__ gcbuf) {
  const int bh = blockIdx.x;
  const int c  = threadIdx.x;
  if (c < NC_) {
    const size_t base = (size_t)bh * N_ + c * C_;
    float acc = 0.f;
    for (int t = 0; t < C_; ++t) { acc += gkbuf[base + t]; gcbuf[base + t] = acc; }
  }
}

// ---------------------------------------------------------------------------
// A[bh,c,t,s] = (s<=t) ? (q_t·k_s)*(1/16)*exp(gc_t-gc_s) : 0
// ---------------------------------------------------------------------------
__global__ __launch_bounds__(256) void a_kernel(const float* __restrict__ q,
    const float* __restrict__ k, const float* __restrict__ gc,
    float* __restrict__ Abuf) {
  const int blk = blockIdx.x;
  const int bh  = blk >> 5, c = blk & 31;
  const int b   = bh >> 2, h = bh & 3;
  __shared__ float qs[64][68];   // qs[t][d_local]
  __shared__ float ks_[64][68];  // ks_[s][d_local]
  __shared__ float gcs[64];
  const int tid = threadIdx.x;
  const int tx = tid & 15, ty = tid >> 4;
  const int lrow = tid >> 2;
  const int lc4  = (tid & 3) * 4;
  if (tid < 64) gcs[tid] = gc[(size_t)bh * N_ + c * C_ + tid];
  const float* qbase = q + (size_t)(b * N_ + c * C_) * (NH_ * DK_) + h * DK_;
  const float* kbase = k + (size_t)(b * N_ + c * C_) * (NH_ * DK_) + h * DK_;
  float acc[4][4] = {};
  for (int dt = 0; dt < 4; ++dt) {
    __syncthreads();
#pragma unroll
    for (int it = 0; it < 4; ++it) {
      int col = lc4 + it * 16;
      *(float4*)&qs[lrow][col]  = *(const float4*)(qbase + (size_t)lrow * (NH_ * DK_) + dt * 64 + col);
      *(float4*)&ks_[lrow][col] = *(const float4*)(kbase + (size_t)lrow * (NH_ * DK_) + dt * 64 + col);
    }
    __syncthreads();
    for (int i = 0; i < 4; ++i)
      for (int j = 0; j < 4; ++j) {
        const int t = ty * 4 + i, s = tx * 4 + j;
        float sm = 0.f;
        for (int d = 0; d < 64; ++d) sm += qs[t][d] * ks_[s][d];
        acc[i][j] += sm;
      }
  }
  float* ab = Abuf + (size_t)blk * 4096;
  const float scl = 0.0625f;   // 1/sqrt(256)
  for (int i = 0; i < 4; ++i) {
    const int t = ty * 4 + i;
    const float gct = gcs[t];
    for (int j = 0; j < 4; ++j) {
      const int s = tx * 4 + j;
      ab[(size_t)t * 64 + s] = (s <= t) ? acc[i][j] * scl * expf(gct - gcs[s]) : 0.f;
    }
  }
}

// ---------------------------------------------------------------------------
// In-place decay prep (after a_kernel consumed raw q,k):
//   q *= (1/16)*exp(gc);  k *= exp(gt - gc)
// ---------------------------------------------------------------------------
__global__ __launch_bounds__(256) void prep_qk(float* __restrict__ q,
    float* __restrict__ k, const float* __restrict__ gc) {
  const size_t idx = (size_t)blockIdx.x * 256 + threadIdx.x;   // < 8192*1024
  const int row = (int)(idx >> 10);
  const int col = (int)(idx & 1023);
  const int b = row >> 11, n = row & 2047;
  const int h = col >> 8;
  const size_t gb = (size_t)(b * NH_ + h) * N_;
  const float gcv = gc[gb + n];
  const float gtv = gc[gb + (n | 63)];
  q[idx] *= 0.0625f * expf(gcv);
  k[idx] *= expf(gtv - gcv);
}

// ---------------------------------------------------------------------------
// Sequential chunk scan (qd,kd pre-scaled).  grid = (16 vblk, 16 bh), 256 thr.
// ---------------------------------------------------------------------------
__global__ __launch_bounds__(256) void scan_kernel(
    const float* __restrict__ qd, const float* __restrict__ kd,
    const float* __restrict__ v, const float* __restrict__ gc,
    const float* __restrict__ Abuf, float* __restrict__ o) {
  const int vblk = blockIdx.x;   // 0..15
  const int bh   = blockIdx.y;   // 0..15
  const int b = bh >> 2, h = bh & 3;
  __shared__ float S[256][33];
  __shared__ float vb[64][36];
  __shared__ float Ab[64][68];
  __shared__ float tl[64][68];
  const int tid = threadIdx.x;
  const int e = tid & 31, rg = tid >> 5;
  const int lrow = tid >> 2;
  const int lc4  = (tid & 3) * 4;

  for (int i = tid; i < 256 * 33; i += 256) (&S[0][0])[i] = 0.f;

  const float* qbase = qd + (size_t)b * N_ * (NH_ * DK_) + h * DK_;
  const float* kbase = kd + (size_t)b * N_ * (NH_ * DK_) + h * DK_;
  const float* vbase = v + (size_t)b * N_ * (NH_ * DV_) + h * DV_ + vblk * 32;
  float*       obase = o + (size_t)b * N_ * (NH_ * DV_) + h * DV_ + vblk * 32;
  const float* abase = Abuf + (size_t)bh * NC_ * 4096;

  for (int c = 0; c < NC_; ++c) {
    const float egt = expf(gc[(size_t)bh * N_ + c * C_ + 63]);
    __syncthreads();
    // ---- stage vb [64][32], Ab [64][64]
    {
      const int row = tid >> 3, f4 = (tid & 7) * 4;
      *(float4*)&vb[row][f4]      = *(const float4*)(vbase + (size_t)(c * C_ + row) * (NH_ * DV_) + f4);
      *(float4*)&vb[row + 32][f4] = *(const float4*)(vbase + (size_t)(c * C_ + row + 32) * (NH_ * DV_) + f4);
      const float* ar = abase + (size_t)c * 4096 + (size_t)lrow * 64;
#pragma unroll
      for (int it = 0; it < 4; ++it) {
        int col = lc4 + it * 16;
        *(float4*)&Ab[lrow][col] = *(const float4*)(ar + col);
      }
    }
    __syncthreads();

    // ---- intra-chunk: oacc[i] = sum_s A[row][s] * v[s][e]
    float oacc[8];
    for (int i = 0; i < 8; ++i) {
      const int row = rg * 8 + i;
      float sm = 0.f;
      for (int s = 0; s < 64; ++s) sm += Ab[row][s] * vb[s][e];
      oacc[i] = sm;
    }

    // ---- inter-chunk: oacc[i] += sum_d qd[row][d] * S[d][e]
    for (int dt = 0; dt < 4; ++dt) {
      __syncthreads();
#pragma unroll
      for (int it = 0; it < 4; ++it) {
        int col = lc4 + it * 16;
        *(float4*)&tl[lrow][col] =
            *(const float4*)(qbase + (size_t)(c * C_ + lrow) * (NH_ * DK_) + dt * 64 + col);
      }
      __syncthreads();
      for (int i = 0; i < 8; ++i) {
        const int row = rg * 8 + i;
        float sm = oacc[i];
        for (int d = 0; d < 64; ++d) sm += tl[row][d] * S[dt * 64 + d][e];
        oacc[i] = sm;
      }
    }

    // ---- write o
    for (int i = 0; i < 8; ++i)
      obase[(size_t)(c * C_ + rg * 8 + i) * (NH_ * DV_) + e] = oacc[i];

    // ---- state update: S = egt * S + kd^T @ v
    for (int dt = 0; dt < 4; ++dt) {
      __syncthreads();
#pragma unroll
      for (int it = 0; it < 4; ++it) {
        int col = lc4 + it * 16;
        *(float4*)&tl[lrow][col] =
            *(const float4*)(kbase + (size_t)(c * C_ + lrow) * (NH_ * DK_) + dt * 64 + col);
      }
      __syncthreads();
      float acc2[8] = {};
      for (int t = 0; t < 64; ++t) {
        const float tv = vb[t][e];
        for (int dl = 0; dl < 8; ++dl) acc2[dl] += tl[t][rg * 8 + dl] * tv;
      }
      for (int dl = 0; dl < 8; ++dl) {
        const int dgl = dt * 64 + rg * 8 + dl;
        S[dgl][e] = S[dgl][e] * egt + acc2[dl];
      }
    }
  }
}

// ---------------------------------------------------------------------------
// o <- RMSNorm(o)*gnorm_w * swish(g), per (row, head) group of 512.
// ---------------------------------------------------------------------------
__global__ __launch_bounds__(256) void normgate_kernel(float* __restrict__ o,
    const float* __restrict__ g, const float* __restrict__ w) {
  const int blk = blockIdx.x;          // row*NH + h
  const int row = blk >> 2, h = blk & 3;
  const size_t base = (size_t)row * (NH_ * DV_) + h * DV_;
  const int tid = threadIdx.x;
  __shared__ float red2[256];
  const float v0 = o[base + tid], v1 = o[base + tid + 256];
  red2[tid] = v0 * v0 + v1 * v1;
  __syncthreads();
  for (int off = 128; off; off >>= 1) {
    if (tid < off) red2[tid] += red2[tid + off];
    __syncthreads();
  }
  const float rms = rsqrtf(red2[0] * (1.0f / 512.0f) + 1e-5f);
  const float g0 = g[base + tid], g1 = g[base + tid + 256];
  const float sw0 = g0 / (1.f + expf(-g0));
  const float sw1 = g1 / (1.f + expf(-g1));
  o[base + tid]       = v0 * rms * w[tid] * sw0;
  o[base + tid + 256] = v1 * rms * w[tid + 256] * sw1;
}

// ---------------------------------------------------------------------------
// Workspace layout (floats), peak 52,494,336 floats = 200.25 MiB:
//   gk : [0        , 32768   )
//   gc : [32768    , 65536   )
//   Ab : [65536    , 2162688 )
//   q  : [2162688  , 10551296)   (scaled in place by prep_qk)
//   k  : [10551296 , 18939904)
//   v  : [18939904 , 35717120)
//   o  : [35717120 , 52494336)
//   g  : aliases q+k region after scan
// ---------------------------------------------------------------------------
extern "C" void kernel_launch(void* const* d_in, const int* in_sizes, int n_in,
                              void* d_out, int out_size, void* d_ws, size_t ws_size,
                              hipStream_t stream) {
  (void)in_sizes; (void)n_in; (void)out_size; (void)ws_size;
  const float* x    = (const float*)d_in[0];
  const float* Wq   = (const float*)d_in[1];
  const float* Wk   = (const float*)d_in[2];
  const float* Wv   = (const float*)d_in[3];
  const float* Wg   = (const float*)d_in[4];
  const float* Wgk  = (const float*)d_in[5];
  const float* bgk  = (const float*)d_in[6];
  const float* Wo   = (const float*)d_in[7];
  const float* gw   = (const float*)d_in[8];

  float* ws = (float*)d_ws;
  float* gk = ws;
  float* gc = gk + (size_t)16 * N_;
  float* Ab = gc + (size_t)16 * N_;
  float* q  = Ab + (size_t)16 * NC_ * 64 * 64;
  float* k  = q  + (size_t)M_ * 1024;
  float* v  = k  + (size_t)M_ * 1024;
  float* o  = v  + (size_t)M_ * 2048;
  float* g  = q;                      // reuses q+k region after scan

  dim3 thr(256);
  gemm_f32<false><<<dim3(1024 / 64, M_ / 64), thr, 0, stream>>>(x, Wq, q, 1024, 1024);
  gemm_f32<false><<<dim3(1024 / 64, M_ / 64), thr, 0, stream>>>(x, Wk, k, 1024, 1024);
  gk_kernel<<<M_, 256, 0, stream>>>(x, Wgk, bgk, gk);
  cumsum_kernel<<<16, 64, 0, stream>>>(gk, gc);
  a_kernel<<<16 * NC_, 256, 0, stream>>>(q, k, gc, Ab);
  prep_qk<<<M_ * 1024 / 256, 256, 0, stream>>>(q, k, gc);
  gemm_f32<false><<<dim3(2048 / 64, M_ / 64), thr, 0, stream>>>(x, Wv, v, 2048, 1024);
  scan_kernel<<<dim3(16, 16), thr, 0, stream>>>(q, k, v, gc, Ab, o);
  gemm_f32<false><<<dim3(2048 / 64, M_ / 64), thr, 0, stream>>>(x, Wg, g, 2048, 1024);
  normgate_kernel<<<M_ * NH_, 256, 0, stream>>>(o, g, gw);
  // FINAL OUTPUT: fp32 store (reference output dtype is float32)
  gemm_f32<false><<<dim3(1024 / 64, M_ / 64), thr, 0, stream>>>(o, Wo, d_out, 1024, 2048);
}

// Round 5
// 1487.606 us; speedup vs baseline: 2.0504x; 2.0504x over previous
//
#include <hip/hip_runtime.h>

// Problem constants (fixed by the reference)
constexpr int B_  = 4;
constexpr int N_  = 2048;
constexpr int HID_ = 1024;
constexpr int NH_ = 4;
constexpr int DK_ = 256;
constexpr int DV_ = 512;
constexpr int C_  = 64;     // chunk size
constexpr int NC_ = 32;     // chunks per sequence
constexpr int M_  = B_ * N_;  // 8192 rows

using ushort_t = unsigned short;
typedef __attribute__((ext_vector_type(8))) short bf16x8;
typedef __attribute__((ext_vector_type(4))) float f32x4;

__device__ __forceinline__ ushort_t f2bf(float f) {
  union { float fv; unsigned u; } v; v.fv = f;
  unsigned r = v.u + 0x7FFFu + ((v.u >> 16) & 1u);   // round-to-nearest-even
  return (ushort_t)(r >> 16);
}

__device__ __forceinline__ void gload_lds16(const void* g, void* l) {
  __builtin_amdgcn_global_load_lds(
      (const __attribute__((address_space(1))) unsigned int*)g,
      (__attribute__((address_space(3))) unsigned int*)l, 16, 0, 0);
}

// ---------------------------------------------------------------------------
// bf16 MFMA GEMM: C[M,N] fp32 = A[M,K] bf16 @ BT[N,K] bf16 (B^T layout).
// 128x128 tile, BK=32, 256 thr = 4 waves (2x2 of 64x64), m97 2-barrier loop.
// M,N multiples of 128; K multiple of 32.
// ---------------------------------------------------------------------------
__global__ __launch_bounds__(256) void gemm_mfma(
    const ushort_t* __restrict__ A, const ushort_t* __restrict__ BT,
    float* __restrict__ C, int N, int K) {
  __shared__ ushort_t Asl[128 * 32];
  __shared__ ushort_t Bsl[128 * 32];
  const int tid = threadIdx.x;
  const int wave = tid >> 6, lane = tid & 63;
  const size_t brow = (size_t)blockIdx.y * 128;
  const size_t bcol = (size_t)blockIdx.x * 128;
  const int wr = (wave >> 1) * 64, wc = (wave & 1) * 64;

  f32x4 acc[4][4];
#pragma unroll
  for (int m = 0; m < 4; ++m)
#pragma unroll
    for (int n = 0; n < 4; ++n) acc[m][n] = f32x4{0.f, 0.f, 0.f, 0.f};

  const int kk   = (lane & 3) * 8;     // staging k within tile
  const int frow = lane & 15;          // fragment row/col
  const int fk   = (lane >> 4) * 8;    // fragment k-slice

  for (int k0 = 0; k0 < K; k0 += 32) {
    // ---- stage A,B tiles via async global->LDS (linear lane order, m104 rule)
#pragma unroll
    for (int j = 0; j < 2; ++j) {
      const int cbase = j * 4 + wave;                 // 0..7 (wave-uniform)
      const int row   = (cbase * 64 + lane) >> 2;     // 0..127
      gload_lds16(A  + (brow + row) * K + k0 + kk, Asl + cbase * 512);
      gload_lds16(BT + (bcol + row) * K + k0 + kk, Bsl + cbase * 512);
    }
    __syncthreads();   // drains vmcnt (compiler inserts waitcnt before barrier)

    bf16x8 af[4], bfr[4];
#pragma unroll
    for (int m = 0; m < 4; ++m)
      af[m] = *(const bf16x8*)(Asl + (wr + m * 16 + frow) * 32 + fk);
#pragma unroll
    for (int n = 0; n < 4; ++n)
      bfr[n] = *(const bf16x8*)(Bsl + (wc + n * 16 + frow) * 32 + fk);
#pragma unroll
    for (int m = 0; m < 4; ++m)
#pragma unroll
      for (int n = 0; n < 4; ++n)
        acc[m][n] = __builtin_amdgcn_mfma_f32_16x16x32_bf16(af[m], bfr[n], acc[m][n], 0, 0, 0);
    __syncthreads();   // protect LDS from next-iter staging
  }

  // C/D layout (m89-verified): col = lane&15, row = (lane>>4)*4 + j
  const int crow = (lane >> 4) * 4;
  const int ccol = lane & 15;
#pragma unroll
  for (int m = 0; m < 4; ++m)
#pragma unroll
    for (int n = 0; n < 4; ++n) {
      float* cp = C + (brow + wr + m * 16 + crow) * N + (bcol + wc + n * 16 + ccol);
#pragma unroll
      for (int j = 0; j < 4; ++j) cp[(size_t)j * N] = acc[m][n][j];
    }
}

// ---------------------------------------------------------------------------
// fp32 -> bf16 elementwise (4 elems/thread)
// ---------------------------------------------------------------------------
__global__ __launch_bounds__(256) void conv_to_bf16(const float* __restrict__ in,
    ushort_t* __restrict__ out) {
  const size_t i = ((size_t)blockIdx.x * 256 + threadIdx.x) * 4;
  float4 v = *(const float4*)(in + i);
  ushort4 r;
  r.x = f2bf(v.x); r.y = f2bf(v.y); r.z = f2bf(v.z); r.w = f2bf(v.w);
  *(ushort4*)(out + i) = r;
}

// ---------------------------------------------------------------------------
// W[K,N] fp32 -> WT[N,K] bf16 (tiled transpose)
// grid = (N/32, K/32), 256 threads
// ---------------------------------------------------------------------------
__global__ __launch_bounds__(256) void transp_bf16(const float* __restrict__ W,
    ushort_t* __restrict__ WT, int K, int N) {
  __shared__ float tile[32][33];
  const int n0 = blockIdx.x * 32, k0 = blockIdx.y * 32;
  const int tx = threadIdx.x & 31, ty = threadIdx.x >> 5;
#pragma unroll
  for (int i = 0; i < 32; i += 8)
    tile[ty + i][tx] = W[(size_t)(k0 + ty + i) * N + n0 + tx];
  __syncthreads();
#pragma unroll
  for (int i = 0; i < 32; i += 8)
    WT[(size_t)(n0 + ty + i) * K + k0 + tx] = f2bf(tile[tx][ty + i]);
}

// ---------------------------------------------------------------------------
// gk[b,h,n] = logsigmoid(x[b,n,:]·Wgk[:,h] + bgk[h]) / 16
// ---------------------------------------------------------------------------
__global__ __launch_bounds__(256) void gk_kernel(const float* __restrict__ x,
    const float* __restrict__ Wgk, const float* __restrict__ bgk,
    float* __restrict__ gkbuf) {
  const int row  = blockIdx.x;         // b*N + n
  const int b    = row / N_;
  const int n    = row - b * N_;
  const int tid  = threadIdx.x;
  const int wv   = tid >> 6;           // head
  const int ln   = tid & 63;
  __shared__ float red2[256];
  const float* xr = x + (size_t)row * HID_;
  float s = 0.f;
  for (int i = ln; i < HID_; i += 64) s += xr[i] * Wgk[i * NH_ + wv];
  red2[tid] = s;
  __syncthreads();
  for (int off = 32; off; off >>= 1) {
    if (ln < off) red2[tid] += red2[tid + off];
    __syncthreads();
  }
  if (ln == 0) {
    float z  = red2[wv * 64] + bgk[wv];
    float ls = fminf(z, 0.f) - log1pf(expf(-fabsf(z)));
    gkbuf[((size_t)(b * NH_ + wv)) * N_ + n] = ls * (1.0f / 16.0f);
  }
}

// ---------------------------------------------------------------------------
// per-(bh,chunk) inclusive cumsum of gk: one thread per chunk, serial.
// ---------------------------------------------------------------------------
__global__ __launch_bounds__(64) void cumsum_kernel(const float* __restrict__ gkbuf,
                                                    float* __restrict__ gcbuf) {
  const int bh = blockIdx.x;
  const int c  = threadIdx.x;
  if (c < NC_) {
    const size_t base = (size_t)bh * N_ + c * C_;
    float acc = 0.f;
    for (int t = 0; t < C_; ++t) { acc += gkbuf[base + t]; gcbuf[base + t] = acc; }
  }
}

// ---------------------------------------------------------------------------
// A[bh,c,t,s] = (s<=t) ? (q_t·k_s)*(1/16)*exp(gc_t-gc_s) : 0
// ---------------------------------------------------------------------------
__global__ __launch_bounds__(256) void a_kernel(const float* __restrict__ q,
    const float* __restrict__ k, const float* __restrict__ gc,
    float* __restrict__ Abuf) {
  const int blk = blockIdx.x;
  const int bh  = blk >> 5, c = blk & 31;
  const int b   = bh >> 2, h = bh & 3;
  __shared__ float qs[64][68];   // qs[t][d_local]
  __shared__ float ks_[64][68];  // ks_[s][d_local]
  __shared__ float gcs[64];
  const int tid = threadIdx.x;
  const int tx = tid & 15, ty = tid >> 4;
  const int lrow = tid >> 2;
  const int lc4  = (tid & 3) * 4;
  if (tid < 64) gcs[tid] = gc[(size_t)bh * N_ + c * C_ + tid];
  const float* qbase = q + (size_t)(b * N_ + c * C_) * (NH_ * DK_) + h * DK_;
  const float* kbase = k + (size_t)(b * N_ + c * C_) * (NH_ * DK_) + h * DK_;
  float acc[4][4] = {};
  for (int dt = 0; dt < 4; ++dt) {
    __syncthreads();
#pragma unroll
    for (int it = 0; it < 4; ++it) {
      int col = lc4 + it * 16;
      *(float4*)&qs[lrow][col]  = *(const float4*)(qbase + (size_t)lrow * (NH_ * DK_) + dt * 64 + col);
      *(float4*)&ks_[lrow][col] = *(const float4*)(kbase + (size_t)lrow * (NH_ * DK_) + dt * 64 + col);
    }
    __syncthreads();
    for (int i = 0; i < 4; ++i)
      for (int j = 0; j < 4; ++j) {
        const int t = ty * 4 + i, s = tx * 4 + j;
        float sm = 0.f;
        for (int d = 0; d < 64; ++d) sm += qs[t][d] * ks_[s][d];
        acc[i][j] += sm;
      }
  }
  float* ab = Abuf + (size_t)blk * 4096;
  const float scl = 0.0625f;   // 1/sqrt(256)
  for (int i = 0; i < 4; ++i) {
    const int t = ty * 4 + i;
    const float gct = gcs[t];
    for (int j = 0; j < 4; ++j) {
      const int s = tx * 4 + j;
      ab[(size_t)t * 64 + s] = (s <= t) ? acc[i][j] * scl * expf(gct - gcs[s]) : 0.f;
    }
  }
}

// ---------------------------------------------------------------------------
// In-place decay prep: q *= (1/16)*exp(gc);  k *= exp(gt - gc)
// ---------------------------------------------------------------------------
__global__ __launch_bounds__(256) void prep_qk(float* __restrict__ q,
    float* __restrict__ k, const float* __restrict__ gc) {
  const size_t idx = (size_t)blockIdx.x * 256 + threadIdx.x;   // < 8192*1024
  const int row = (int)(idx >> 10);
  const int col = (int)(idx & 1023);
  const int b = row >> 11, n = row & 2047;
  const int h = col >> 8;
  const size_t gb = (size_t)(b * NH_ + h) * N_;
  const float gcv = gc[gb + n];
  const float gtv = gc[gb + (n | 63)];
  q[idx] *= 0.0625f * expf(gcv);
  k[idx] *= expf(gtv - gcv);
}

// ---------------------------------------------------------------------------
// Sequential chunk scan (qd,kd pre-scaled).  grid = (16 vblk, 16 bh), 256 thr.
// ---------------------------------------------------------------------------
__global__ __launch_bounds__(256) void scan_kernel(
    const float* __restrict__ qd, const float* __restrict__ kd,
    const float* __restrict__ v, const float* __restrict__ gc,
    const float* __restrict__ Abuf, float* __restrict__ o) {
  const int vblk = blockIdx.x;   // 0..15
  const int bh   = blockIdx.y;   // 0..15
  const int b = bh >> 2, h = bh & 3;
  __shared__ float S[256][33];
  __shared__ float vb[64][36];
  __shared__ float Ab[64][68];
  __shared__ float tl[64][68];
  const int tid = threadIdx.x;
  const int e = tid & 31, rg = tid >> 5;
  const int lrow = tid >> 2;
  const int lc4  = (tid & 3) * 4;

  for (int i = tid; i < 256 * 33; i += 256) (&S[0][0])[i] = 0.f;

  const float* qbase = qd + (size_t)b * N_ * (NH_ * DK_) + h * DK_;
  const float* kbase = kd + (size_t)b * N_ * (NH_ * DK_) + h * DK_;
  const float* vbase = v + (size_t)b * N_ * (NH_ * DV_) + h * DV_ + vblk * 32;
  float*       obase = o + (size_t)b * N_ * (NH_ * DV_) + h * DV_ + vblk * 32;
  const float* abase = Abuf + (size_t)bh * NC_ * 4096;

  for (int c = 0; c < NC_; ++c) {
    const float egt = expf(gc[(size_t)bh * N_ + c * C_ + 63]);
    __syncthreads();
    {
      const int row = tid >> 3, f4 = (tid & 7) * 4;
      *(float4*)&vb[row][f4]      = *(const float4*)(vbase + (size_t)(c * C_ + row) * (NH_ * DV_) + f4);
      *(float4*)&vb[row + 32][f4] = *(const float4*)(vbase + (size_t)(c * C_ + row + 32) * (NH_ * DV_) + f4);
      const float* ar = abase + (size_t)c * 4096 + (size_t)lrow * 64;
#pragma unroll
      for (int it = 0; it < 4; ++it) {
        int col = lc4 + it * 16;
        *(float4*)&Ab[lrow][col] = *(const float4*)(ar + col);
      }
    }
    __syncthreads();

    float oacc[8];
    for (int i = 0; i < 8; ++i) {
      const int row = rg * 8 + i;
      float sm = 0.f;
      for (int s = 0; s < 64; ++s) sm += Ab[row][s] * vb[s][e];
      oacc[i] = sm;
    }

    for (int dt = 0; dt < 4; ++dt) {
      __syncthreads();
#pragma unroll
      for (int it = 0; it < 4; ++it) {
        int col = lc4 + it * 16;
        *(float4*)&tl[lrow][col] =
            *(const float4*)(qbase + (size_t)(c * C_ + lrow) * (NH_ * DK_) + dt * 64 + col);
      }
      __syncthreads();
      for (int i = 0; i < 8; ++i) {
        const int row = rg * 8 + i;
        float sm = oacc[i];
        for (int d = 0; d < 64; ++d) sm += tl[row][d] * S[dt * 64 + d][e];
        oacc[i] = sm;
      }
    }

    for (int i = 0; i < 8; ++i)
      obase[(size_t)(c * C_ + rg * 8 + i) * (NH_ * DV_) + e] = oacc[i];

    for (int dt = 0; dt < 4; ++dt) {
      __syncthreads();
#pragma unroll
      for (int it = 0; it < 4; ++it) {
        int col = lc4 + it * 16;
        *(float4*)&tl[lrow][col] =
            *(const float4*)(kbase + (size_t)(c * C_ + lrow) * (NH_ * DK_) + dt * 64 + col);
      }
      __syncthreads();
      float acc2[8] = {};
      for (int t = 0; t < 64; ++t) {
        const float tv = vb[t][e];
        for (int dl = 0; dl < 8; ++dl) acc2[dl] += tl[t][rg * 8 + dl] * tv;
      }
      for (int dl = 0; dl < 8; ++dl) {
        const int dgl = dt * 64 + rg * 8 + dl;
        S[dgl][e] = S[dgl][e] * egt + acc2[dl];
      }
    }
  }
}

// ---------------------------------------------------------------------------
// ob(bf16) <- RMSNorm(o)*gnorm_w * swish(g), per (row, head) group of 512.
// ---------------------------------------------------------------------------
__global__ __launch_bounds__(256) void normgate_kernel(const float* __restrict__ o,
    const float* __restrict__ g, const float* __restrict__ w,
    ushort_t* __restrict__ ob) {
  const int blk = blockIdx.x;          // row*NH + h
  const size_t base = (size_t)blk * DV_;
  const int tid = threadIdx.x;
  __shared__ float red2[256];
  const float v0 = o[base + tid], v1 = o[base + tid + 256];
  red2[tid] = v0 * v0 + v1 * v1;
  __syncthreads();
  for (int off = 128; off; off >>= 1) {
    if (tid < off) red2[tid] += red2[tid + off];
    __syncthreads();
  }
  const float rms = rsqrtf(red2[0] * (1.0f / 512.0f) + 1e-5f);
  const float g0 = g[base + tid], g1 = g[base + tid + 256];
  const float sw0 = g0 / (1.f + expf(-g0));
  const float sw1 = g1 / (1.f + expf(-g1));
  ob[base + tid]       = f2bf(v0 * rms * w[tid] * sw0);
  ob[base + tid + 256] = f2bf(v1 * rms * w[tid + 256] * sw1);
}

// ---------------------------------------------------------------------------
// Workspace layout (float units), total 60,882,944 floats = 232.25 MiB:
//   gk 32K | gc 32K | Ab 2M | q 8M | k 8M | v 16M | o 16M |
//   xb 4M | WqT 512K | WkT 512K | WvT 1M | WgT 1M | WoT 1M
//   g(fp32) aliases q+k after scan; ob(bf16) aliases v after scan.
// ---------------------------------------------------------------------------
extern "C" void kernel_launch(void* const* d_in, const int* in_sizes, int n_in,
                              void* d_out, int out_size, void* d_ws, size_t ws_size,
                              hipStream_t stream) {
  (void)in_sizes; (void)n_in; (void)out_size; (void)ws_size;
  const float* x    = (const float*)d_in[0];
  const float* Wq   = (const float*)d_in[1];
  const float* Wk   = (const float*)d_in[2];
  const float* Wv   = (const float*)d_in[3];
  const float* Wg   = (const float*)d_in[4];
  const float* Wgk  = (const float*)d_in[5];
  const float* bgk  = (const float*)d_in[6];
  const float* Wo   = (const float*)d_in[7];
  const float* gw   = (const float*)d_in[8];

  float* ws = (float*)d_ws;
  size_t off = 0;
  float* gk = ws + off; off += (size_t)16 * N_;
  float* gc = ws + off; off += (size_t)16 * N_;
  float* Ab = ws + off; off += (size_t)16 * NC_ * 4096;
  float* q  = ws + off; off += (size_t)M_ * 1024;
  float* k  = ws + off; off += (size_t)M_ * 1024;
  float* v  = ws + off; off += (size_t)M_ * 2048;
  float* o  = ws + off; off += (size_t)M_ * 2048;
  ushort_t* xb  = (ushort_t*)(ws + off); off += (size_t)M_ * HID_ / 2;
  ushort_t* WqT = (ushort_t*)(ws + off); off += (size_t)1024 * 1024 / 2;
  ushort_t* WkT = (ushort_t*)(ws + off); off += (size_t)1024 * 1024 / 2;
  ushort_t* WvT = (ushort_t*)(ws + off); off += (size_t)2048 * 1024 / 2;
  ushort_t* WgT = (ushort_t*)(ws + off); off += (size_t)2048 * 1024 / 2;
  ushort_t* WoT = (ushort_t*)(ws + off); off += (size_t)1024 * 2048 / 2;
  float*    g   = q;              // reuses q+k region after scan
  ushort_t* ob  = (ushort_t*)v;   // reuses v region after scan

  dim3 thr(256);
  // bf16 conversions / transposes
  conv_to_bf16<<<M_ * HID_ / 1024, thr, 0, stream>>>(x, xb);
  transp_bf16<<<dim3(32, 32), thr, 0, stream>>>(Wq, WqT, 1024, 1024);
  transp_bf16<<<dim3(32, 32), thr, 0, stream>>>(Wk, WkT, 1024, 1024);
  transp_bf16<<<dim3(64, 32), thr, 0, stream>>>(Wv, WvT, 1024, 2048);
  transp_bf16<<<dim3(64, 32), thr, 0, stream>>>(Wg, WgT, 1024, 2048);
  transp_bf16<<<dim3(32, 64), thr, 0, stream>>>(Wo, WoT, 2048, 1024);

  // projections (bf16 MFMA, fp32 out)
  gemm_mfma<<<dim3(1024 / 128, M_ / 128), thr, 0, stream>>>(xb, WqT, q, 1024, 1024);
  gemm_mfma<<<dim3(1024 / 128, M_ / 128), thr, 0, stream>>>(xb, WkT, k, 1024, 1024);
  gk_kernel<<<M_, thr, 0, stream>>>(x, Wgk, bgk, gk);
  cumsum_kernel<<<16, 64, 0, stream>>>(gk, gc);
  a_kernel<<<16 * NC_, thr, 0, stream>>>(q, k, gc, Ab);
  prep_qk<<<M_ * 1024 / 256, thr, 0, stream>>>(q, k, gc);
  gemm_mfma<<<dim3(2048 / 128, M_ / 128), thr, 0, stream>>>(xb, WvT, v, 2048, 1024);
  scan_kernel<<<dim3(16, 16), thr, 0, stream>>>(q, k, v, gc, Ab, o);
  gemm_mfma<<<dim3(2048 / 128, M_ / 128), thr, 0, stream>>>(xb, WgT, g, 2048, 1024);
  normgate_kernel<<<M_ * NH_, thr, 0, stream>>>(o, g, gw, ob);
  gemm_mfma<<<dim3(1024 / 128, M_ / 128), thr, 0, stream>>>(ob, WoT, (float*)d_out, 1024, 2048);
}

// Round 6
// 594.704 us; speedup vs baseline: 5.1289x; 2.5014x over previous
//
#include <hip/hip_runtime.h>

// Problem constants (fixed by the reference)
constexpr int B_  = 4;
constexpr int N_  = 2048;
constexpr int HID_ = 1024;
constexpr int NH_ = 4;
constexpr int DK_ = 256;
constexpr int DV_ = 512;
constexpr int C_  = 64;     // chunk size
constexpr int NC_ = 32;     // chunks per sequence
constexpr int M_  = B_ * N_;  // 8192 rows

using ushort_t = unsigned short;
typedef __attribute__((ext_vector_type(8))) short bf16x8;
typedef __attribute__((ext_vector_type(4))) float f32x4;

__device__ __forceinline__ ushort_t f2bf(float f) {
  union { float fv; unsigned u; } v; v.fv = f;
  unsigned r = v.u + 0x7FFFu + ((v.u >> 16) & 1u);   // round-to-nearest-even
  return (ushort_t)(r >> 16);
}
__device__ __forceinline__ float bf2f(ushort_t u) {
  union { unsigned u; float f; } v; v.u = ((unsigned)u) << 16; return v.f;
}

__device__ __forceinline__ void gload_lds16(const void* g, void* l) {
  __builtin_amdgcn_global_load_lds(
      (const __attribute__((address_space(1))) unsigned int*)g,
      (__attribute__((address_space(3))) unsigned int*)l, 16, 0, 0);
}

__device__ __forceinline__ f32x4 mfma16(bf16x8 a, bf16x8 b, f32x4 c) {
  return __builtin_amdgcn_mfma_f32_16x16x32_bf16(a, b, c, 0, 0, 0);
}

// ---------------------------------------------------------------------------
// bf16 MFMA GEMM: C[M,N] = A[M,K] bf16 @ BT[N,K] bf16.  Out fp32 or bf16.
// 128x128 tile, BK=32, 256 thr = 4 waves, m97 2-barrier loop.
// ---------------------------------------------------------------------------
template<bool BF16OUT>
__global__ __launch_bounds__(256) void gemm_mfma(
    const ushort_t* __restrict__ A, const ushort_t* __restrict__ BT,
    void* __restrict__ CV, int N, int K) {
  __shared__ ushort_t Asl[128 * 32];
  __shared__ ushort_t Bsl[128 * 32];
  const int tid = threadIdx.x;
  const int wave = tid >> 6, lane = tid & 63;
  const size_t brow = (size_t)blockIdx.y * 128;
  const size_t bcol = (size_t)blockIdx.x * 128;
  const int wr = (wave >> 1) * 64, wc = (wave & 1) * 64;

  f32x4 acc[4][4];
#pragma unroll
  for (int m = 0; m < 4; ++m)
#pragma unroll
    for (int n = 0; n < 4; ++n) acc[m][n] = f32x4{0.f, 0.f, 0.f, 0.f};

  const int kk   = (lane & 3) * 8;     // staging k within tile
  const int frow = lane & 15;          // fragment row/col
  const int fk   = (lane >> 4) * 8;    // fragment k-slice

  for (int k0 = 0; k0 < K; k0 += 32) {
#pragma unroll
    for (int j = 0; j < 2; ++j) {
      const int cbase = j * 4 + wave;                 // 0..7 (wave-uniform)
      const int row   = (cbase * 64 + lane) >> 2;     // 0..127
      gload_lds16(A  + (brow + row) * K + k0 + kk, Asl + cbase * 512);
      gload_lds16(BT + (bcol + row) * K + k0 + kk, Bsl + cbase * 512);
    }
    __syncthreads();

    bf16x8 af[4], bfr[4];
#pragma unroll
    for (int m = 0; m < 4; ++m)
      af[m] = *(const bf16x8*)(Asl + (wr + m * 16 + frow) * 32 + fk);
#pragma unroll
    for (int n = 0; n < 4; ++n)
      bfr[n] = *(const bf16x8*)(Bsl + (wc + n * 16 + frow) * 32 + fk);
#pragma unroll
    for (int m = 0; m < 4; ++m)
#pragma unroll
      for (int n = 0; n < 4; ++n)
        acc[m][n] = mfma16(af[m], bfr[n], acc[m][n]);
    __syncthreads();
  }

  const int crow = (lane >> 4) * 4;
  const int ccol = lane & 15;
#pragma unroll
  for (int m = 0; m < 4; ++m)
#pragma unroll
    for (int n = 0; n < 4; ++n) {
      const size_t base = (brow + wr + m * 16 + crow) * (size_t)N + (bcol + wc + n * 16 + ccol);
      if constexpr (BF16OUT) {
        ushort_t* Out = (ushort_t*)CV;
#pragma unroll
        for (int j = 0; j < 4; ++j) Out[base + (size_t)j * N] = f2bf(acc[m][n][j]);
      } else {
        float* Out = (float*)CV;
#pragma unroll
        for (int j = 0; j < 4; ++j) Out[base + (size_t)j * N] = acc[m][n][j];
      }
    }
}

// ---------------------------------------------------------------------------
// fp32 -> bf16 elementwise (4 elems/thread)
// ---------------------------------------------------------------------------
__global__ __launch_bounds__(256) void conv_to_bf16(const float* __restrict__ in,
    ushort_t* __restrict__ out) {
  const size_t i = ((size_t)blockIdx.x * 256 + threadIdx.x) * 4;
  float4 v = *(const float4*)(in + i);
  ushort4 r;
  r.x = f2bf(v.x); r.y = f2bf(v.y); r.z = f2bf(v.z); r.w = f2bf(v.w);
  *(ushort4*)(out + i) = r;
}

// ---------------------------------------------------------------------------
// W[K,N] fp32 -> WT[N,K] bf16 (tiled transpose)
// ---------------------------------------------------------------------------
__global__ __launch_bounds__(256) void transp_bf16(const float* __restrict__ W,
    ushort_t* __restrict__ WT, int K, int N) {
  __shared__ float tile[32][33];
  const int n0 = blockIdx.x * 32, k0 = blockIdx.y * 32;
  const int tx = threadIdx.x & 31, ty = threadIdx.x >> 5;
#pragma unroll
  for (int i = 0; i < 32; i += 8)
    tile[ty + i][tx] = W[(size_t)(k0 + ty + i) * N + n0 + tx];
  __syncthreads();
#pragma unroll
  for (int i = 0; i < 32; i += 8)
    WT[(size_t)(n0 + ty + i) * K + k0 + tx] = f2bf(tile[tx][ty + i]);
}

// ---------------------------------------------------------------------------
// gk[b,h,n] = logsigmoid(x[b,n,:]·Wgk[:,h] + bgk[h]) / 16
// ---------------------------------------------------------------------------
__global__ __launch_bounds__(256) void gk_kernel(const float* __restrict__ x,
    const float* __restrict__ Wgk, const float* __restrict__ bgk,
    float* __restrict__ gkbuf) {
  const int row  = blockIdx.x;
  const int b    = row / N_;
  const int n    = row - b * N_;
  const int tid  = threadIdx.x;
  const int wv   = tid >> 6;
  const int ln   = tid & 63;
  __shared__ float red2[256];
  const float* xr = x + (size_t)row * HID_;
  float s = 0.f;
  for (int i = ln; i < HID_; i += 64) s += xr[i] * Wgk[i * NH_ + wv];
  red2[tid] = s;
  __syncthreads();
  for (int off = 32; off; off >>= 1) {
    if (ln < off) red2[tid] += red2[tid + off];
    __syncthreads();
  }
  if (ln == 0) {
    float z  = red2[wv * 64] + bgk[wv];
    float ls = fminf(z, 0.f) - log1pf(expf(-fabsf(z)));
    gkbuf[((size_t)(b * NH_ + wv)) * N_ + n] = ls * (1.0f / 16.0f);
  }
}

// ---------------------------------------------------------------------------
// per-(bh,chunk) inclusive cumsum of gk
// ---------------------------------------------------------------------------
__global__ __launch_bounds__(64) void cumsum_kernel(const float* __restrict__ gkbuf,
                                                    float* __restrict__ gcbuf) {
  const int bh = blockIdx.x;
  const int c  = threadIdx.x;
  if (c < NC_) {
    const size_t base = (size_t)bh * N_ + c * C_;
    float acc = 0.f;
    for (int t = 0; t < C_; ++t) { acc += gkbuf[base + t]; gcbuf[base + t] = acc; }
  }
}

// ---------------------------------------------------------------------------
// A[bh,c,t,s] = (s<=t) ? (q_t·k_s)*(1/16)*exp(gc_t-gc_s) : 0  -> bf16
// ---------------------------------------------------------------------------
__global__ __launch_bounds__(256) void a_kernel(const float* __restrict__ q,
    const float* __restrict__ k, const float* __restrict__ gc,
    ushort_t* __restrict__ Abuf) {
  const int blk = blockIdx.x;
  const int bh  = blk >> 5, c = blk & 31;
  const int b   = bh >> 2, h = bh & 3;
  __shared__ float qs[64][68];
  __shared__ float ks_[64][68];
  __shared__ float gcs[64];
  const int tid = threadIdx.x;
  const int tx = tid & 15, ty = tid >> 4;
  const int lrow = tid >> 2;
  const int lc4  = (tid & 3) * 4;
  if (tid < 64) gcs[tid] = gc[(size_t)bh * N_ + c * C_ + tid];
  const float* qbase = q + (size_t)(b * N_ + c * C_) * (NH_ * DK_) + h * DK_;
  const float* kbase = k + (size_t)(b * N_ + c * C_) * (NH_ * DK_) + h * DK_;
  float acc[4][4] = {};
  for (int dt = 0; dt < 4; ++dt) {
    __syncthreads();
#pragma unroll
    for (int it = 0; it < 4; ++it) {
      int col = lc4 + it * 16;
      *(float4*)&qs[lrow][col]  = *(const float4*)(qbase + (size_t)lrow * (NH_ * DK_) + dt * 64 + col);
      *(float4*)&ks_[lrow][col] = *(const float4*)(kbase + (size_t)lrow * (NH_ * DK_) + dt * 64 + col);
    }
    __syncthreads();
    for (int i = 0; i < 4; ++i)
      for (int j = 0; j < 4; ++j) {
        const int t = ty * 4 + i, s = tx * 4 + j;
        float sm = 0.f;
        for (int d = 0; d < 64; ++d) sm += qs[t][d] * ks_[s][d];
        acc[i][j] += sm;
      }
  }
  ushort_t* ab = Abuf + (size_t)blk * 4096;
  const float scl = 0.0625f;
  for (int i = 0; i < 4; ++i) {
    const int t = ty * 4 + i;
    const float gct = gcs[t];
    ushort4 r;
    float v0 = (tx * 4 + 0 <= t) ? acc[i][0] * scl * expf(gct - gcs[tx * 4 + 0]) : 0.f;
    float v1 = (tx * 4 + 1 <= t) ? acc[i][1] * scl * expf(gct - gcs[tx * 4 + 1]) : 0.f;
    float v2 = (tx * 4 + 2 <= t) ? acc[i][2] * scl * expf(gct - gcs[tx * 4 + 2]) : 0.f;
    float v3 = (tx * 4 + 3 <= t) ? acc[i][3] * scl * expf(gct - gcs[tx * 4 + 3]) : 0.f;
    r.x = f2bf(v0); r.y = f2bf(v1); r.z = f2bf(v2); r.w = f2bf(v3);
    *(ushort4*)(ab + (size_t)t * 64 + tx * 4) = r;
  }
}

// ---------------------------------------------------------------------------
// q16[row][col] = bf16( q * (1/16) * e^gc )   (layout as q: [8192][1024])
// ---------------------------------------------------------------------------
__global__ __launch_bounds__(256) void pack_q16(const float* __restrict__ q,
    const float* __restrict__ gc, ushort_t* __restrict__ q16) {
  const size_t i4 = ((size_t)blockIdx.x * 256 + threadIdx.x) * 4;
  const int row = (int)(i4 >> 10);
  const int col = (int)(i4 & 1023);
  const int b = row >> 11, n = row & 2047;
  const int h = col >> 8;
  const float f = 0.0625f * expf(gc[(size_t)(b * NH_ + h) * N_ + n]);
  float4 v = *(const float4*)(q + i4);
  ushort4 r;
  r.x = f2bf(v.x * f); r.y = f2bf(v.y * f); r.z = f2bf(v.z * f); r.w = f2bf(v.w * f);
  *(ushort4*)(q16 + i4) = r;
}

// ---------------------------------------------------------------------------
// kT[bh][c][d 256][t 64] = bf16( k[t][d] * e^(gt - gc_t) )  — LDS transpose
// grid = 512 (bh*32+c), 256 thr
// ---------------------------------------------------------------------------
__global__ __launch_bounds__(256) void pack_kT(const float* __restrict__ k,
    const float* __restrict__ gc, ushort_t* __restrict__ kT) {
  const int blk = blockIdx.x;
  const int bh = blk >> 5, c = blk & 31;
  const int b = bh >> 2, h = bh & 3;
  __shared__ ushort_t kl[256][68];
  __shared__ float fk[64];
  const int tid = threadIdx.x;
  if (tid < 64) {
    const float gct = gc[(size_t)bh * N_ + c * C_ + tid];
    const float gt  = gc[(size_t)bh * N_ + c * C_ + 63];
    fk[tid] = expf(gt - gct);
  }
  __syncthreads();
  const float* kb = k + (size_t)(b * N_ + c * C_) * 1024 + h * 256;
  for (int it = 0; it < 16; ++it) {
    const int e = it * 256 + tid;          // 4096 float4 slots
    const int t = e >> 6, d4 = (e & 63) * 4;
    float4 kv = *(const float4*)(kb + (size_t)t * 1024 + d4);
    const float f = fk[t];
    kl[d4 + 0][t] = f2bf(kv.x * f);
    kl[d4 + 1][t] = f2bf(kv.y * f);
    kl[d4 + 2][t] = f2bf(kv.z * f);
    kl[d4 + 3][t] = f2bf(kv.w * f);
  }
  __syncthreads();
  ushort_t* out = kT + (size_t)blk * 16384;
  for (int it = 0; it < 8; ++it) {
    const int e = it * 256 + tid;          // 2048 8B slots
    const int d = e >> 3, t8 = (e & 7) * 8;
    ushort4 lo, hi;
    lo.x = kl[d][t8 + 0]; lo.y = kl[d][t8 + 1]; lo.z = kl[d][t8 + 2]; lo.w = kl[d][t8 + 3];
    hi.x = kl[d][t8 + 4]; hi.y = kl[d][t8 + 5]; hi.z = kl[d][t8 + 6]; hi.w = kl[d][t8 + 7];
    *(ushort4*)(out + (size_t)d * 64 + t8)     = lo;
    *(ushort4*)(out + (size_t)d * 64 + t8 + 4) = hi;
  }
}

// ---------------------------------------------------------------------------
// vT[bh][e 512][n 2048] = v16[b, n, h*512+e]  — LDS transpose
// grid = 1024 (bh*64 + c*2 + eh), 256 thr; tile [64 s][256 e]
// ---------------------------------------------------------------------------
__global__ __launch_bounds__(256) void pack_vT(const ushort_t* __restrict__ v16,
    ushort_t* __restrict__ vT) {
  const int blk = blockIdx.x;
  const int eh = blk & 1, c = (blk >> 1) & 31, bh = blk >> 6;
  const int b = bh >> 2, h = bh & 3;
  __shared__ ushort_t vl[256][68];
  const int tid = threadIdx.x;
  const ushort_t* vb = v16 + (size_t)(b * N_ + c * C_) * 2048 + h * 512 + eh * 256;
  for (int it = 0; it < 8; ++it) {
    const int e = it * 256 + tid;          // 2048 16B slots (64 s x 32 per row)
    const int s = e >> 5, c8 = (e & 31) * 8;
    bf16x8 val = *(const bf16x8*)(vb + (size_t)s * 2048 + c8);
#pragma unroll
    for (int j = 0; j < 8; ++j) vl[c8 + j][s] = (ushort_t)val[j];
  }
  __syncthreads();
  ushort_t* out = vT + (size_t)bh * 512 * 2048 + (size_t)(eh * 256) * 2048 + c * C_;
  for (int it = 0; it < 8; ++it) {
    const int e = it * 256 + tid;          // 2048 8B slots
    const int r = e >> 3, t8 = (e & 7) * 8;
    ushort4 lo, hi;
    lo.x = vl[r][t8 + 0]; lo.y = vl[r][t8 + 1]; lo.z = vl[r][t8 + 2]; lo.w = vl[r][t8 + 3];
    hi.x = vl[r][t8 + 4]; hi.y = vl[r][t8 + 5]; hi.z = vl[r][t8 + 6]; hi.w = vl[r][t8 + 7];
    *(ushort4*)(out + (size_t)r * 2048 + t8)     = lo;
    *(ushort4*)(out + (size_t)r * 2048 + t8 + 4) = hi;
  }
}

// ---------------------------------------------------------------------------
// MFMA chunk scan.  grid = (16 vblk of 32 cols, 16 bh), 256 thr = 4 waves.
// S[256 d][32 e] lives in fp32 accumulator frags (wave w owns d rows w*64..+64).
// Per chunk: o = A@v + q@Sb (Sb = bf16 S^T in LDS), S = e^gt*S + kT@v.
// All A/B operand frags except Sb are direct global 16B loads.
// ---------------------------------------------------------------------------
__global__ __launch_bounds__(256) void scan_mfma(
    const ushort_t* __restrict__ q16,   // [8192][1024] pre-scaled bf16
    const ushort_t* __restrict__ kT,    // [bh][c][256][64] decayed bf16
    const ushort_t* __restrict__ vT,    // [bh][512][2048] bf16
    const ushort_t* __restrict__ ab,    // [bh*32+c][64][64] bf16
    const float*    __restrict__ gc,
    ushort_t* __restrict__ o) {         // [8192][2048] bf16
  const int vblk = blockIdx.x, bh = blockIdx.y;
  const int b = bh >> 2, h = bh & 3;
  const int e0 = vblk * 32;
  __shared__ ushort_t sbt[32][264];     // S^T bf16, pad 8 (row stride 528B)
  const int tid = threadIdx.x;
  const int w = tid >> 6, l = tid & 63;
  const int frow = l & 15, fgrp = l >> 4;

  // zero sbt
  for (int i = tid; i < 32 * 264 / 2; i += 256) ((unsigned*)&sbt[0][0])[i] = 0u;
  f32x4 s_acc[4][2];
#pragma unroll
  for (int sm = 0; sm < 4; ++sm)
#pragma unroll
    for (int sn = 0; sn < 2; ++sn) s_acc[sm][sn] = f32x4{0.f, 0.f, 0.f, 0.f};
  __syncthreads();

  const ushort_t* qbase = q16 + (size_t)(b * N_) * 1024 + h * 256;
  const ushort_t* kbase = kT + (size_t)bh * NC_ * 16384;
  const ushort_t* vbase = vT + (size_t)bh * 512 * 2048 + (size_t)e0 * 2048;
  const ushort_t* abase = ab + (size_t)bh * NC_ * 4096;
  ushort_t*       obase = o + (size_t)(b * N_) * 2048 + h * 512 + e0;

  for (int c = 0; c < NC_; ++c) {
    const float egt = expf(gc[(size_t)bh * N_ + c * C_ + 63]);
    // v B-frags for this chunk: bv[k-slice][n], reused in phases a and c
    bf16x8 bv[2][2];
#pragma unroll
    for (int kk = 0; kk < 2; ++kk)
#pragma unroll
      for (int n2 = 0; n2 < 2; ++n2)
        bv[kk][n2] = *(const bf16x8*)(vbase + (size_t)(n2 * 16 + frow) * 2048 +
                                      c * C_ + kk * 32 + fgrp * 8);
    // ---- phase a: o = A @ v  (wave w: o rows w*16..+16)
    f32x4 oa[2];
    oa[0] = f32x4{0.f, 0.f, 0.f, 0.f};
    oa[1] = f32x4{0.f, 0.f, 0.f, 0.f};
#pragma unroll
    for (int kk = 0; kk < 2; ++kk) {
      bf16x8 aa = *(const bf16x8*)(abase + (size_t)c * 4096 +
                                   (w * 16 + frow) * 64 + kk * 32 + fgrp * 8);
#pragma unroll
      for (int n2 = 0; n2 < 2; ++n2) oa[n2] = mfma16(aa, bv[kk][n2], oa[n2]);
    }
    // ---- phase b: o += q @ S (Sb = bf16 S^T from LDS)
#pragma unroll
    for (int kk = 0; kk < 8; ++kk) {
      bf16x8 aq = *(const bf16x8*)(qbase + (size_t)(c * C_ + w * 16 + frow) * 1024 +
                                   kk * 32 + fgrp * 8);
#pragma unroll
      for (int n2 = 0; n2 < 2; ++n2) {
        bf16x8 bs = *(const bf16x8*)(&sbt[n2 * 16 + frow][kk * 32 + fgrp * 8]);
        oa[n2] = mfma16(aq, bs, oa[n2]);
      }
    }
    // ---- write o (bf16)
#pragma unroll
    for (int n2 = 0; n2 < 2; ++n2)
#pragma unroll
      for (int j = 0; j < 4; ++j)
        obase[(size_t)(c * C_ + w * 16 + fgrp * 4 + j) * 2048 + n2 * 16 + frow] =
            f2bf(oa[n2][j]);
    __syncthreads();   // all sbt reads of this chunk done
    // ---- phase c: S = e^gt * S + kT @ v   (wave w: d rows w*64..+64)
#pragma unroll
    for (int sm = 0; sm < 4; ++sm)
#pragma unroll
      for (int sn = 0; sn < 2; ++sn)
#pragma unroll
        for (int j = 0; j < 4; ++j) s_acc[sm][sn][j] *= egt;
#pragma unroll
    for (int kt = 0; kt < 2; ++kt)
#pragma unroll
      for (int sm = 0; sm < 4; ++sm) {
        bf16x8 ak = *(const bf16x8*)(kbase + (size_t)c * 16384 +
                                     (size_t)(w * 64 + sm * 16 + frow) * 64 +
                                     kt * 32 + fgrp * 8);
#pragma unroll
        for (int sn = 0; sn < 2; ++sn)
          s_acc[sm][sn] = mfma16(ak, bv[kt][sn], s_acc[sm][sn]);
      }
    // ---- publish S^T as bf16 for next chunk's phase b
#pragma unroll
    for (int sm = 0; sm < 4; ++sm)
#pragma unroll
      for (int sn = 0; sn < 2; ++sn) {
        ushort4 pk;
        pk.x = f2bf(s_acc[sm][sn][0]); pk.y = f2bf(s_acc[sm][sn][1]);
        pk.z = f2bf(s_acc[sm][sn][2]); pk.w = f2bf(s_acc[sm][sn][3]);
        *(ushort4*)&sbt[sn * 16 + frow][w * 64 + sm * 16 + fgrp * 4] = pk;
      }
    __syncthreads();   // sbt ready
  }
}

// ---------------------------------------------------------------------------
// ob(bf16) <- RMSNorm(o bf16)*gnorm_w * swish(g fp32)
// ---------------------------------------------------------------------------
__global__ __launch_bounds__(256) void normgate_kernel(const ushort_t* __restrict__ o,
    const float* __restrict__ g, const float* __restrict__ w,
    ushort_t* __restrict__ ob) {
  const int blk = blockIdx.x;
  const size_t base = (size_t)blk * DV_;
  const int tid = threadIdx.x;
  __shared__ float red2[256];
  const float v0 = bf2f(o[base + tid]), v1 = bf2f(o[base + tid + 256]);
  red2[tid] = v0 * v0 + v1 * v1;
  __syncthreads();
  for (int off = 128; off; off >>= 1) {
    if (tid < off) red2[tid] += red2[tid + off];
    __syncthreads();
  }
  const float rms = rsqrtf(red2[0] * (1.0f / 512.0f) + 1e-5f);
  const float g0 = g[base + tid], g1 = g[base + tid + 256];
  const float sw0 = g0 / (1.f + expf(-g0));
  const float sw1 = g1 / (1.f + expf(-g1));
  ob[base + tid]       = f2bf(v0 * rms * w[tid] * sw0);
  ob[base + tid + 256] = f2bf(v1 * rms * w[tid + 256] * sw1);
}

// ---------------------------------------------------------------------------
// Workspace (float units), total 51,445,760 fl = 196.25 MiB:
//   gk 32K | gc 32K | q 8M | k 8M | v16 4M | o 4M | ab16 1.05M |
//   q16 4.19M | kT 4.19M | vT 8.39M | xb 4M | WqT .5 | WkT .5 | WvT 1 | WgT 1 | WoT 1
//   g(fp32,16M) aliases q+k after packs; ob(bf16) aliases q16+kT after scan.
// ---------------------------------------------------------------------------
extern "C" void kernel_launch(void* const* d_in, const int* in_sizes, int n_in,
                              void* d_out, int out_size, void* d_ws, size_t ws_size,
                              hipStream_t stream) {
  (void)in_sizes; (void)n_in; (void)out_size; (void)ws_size;
  const float* x    = (const float*)d_in[0];
  const float* Wq   = (const float*)d_in[1];
  const float* Wk   = (const float*)d_in[2];
  const float* Wv   = (const float*)d_in[3];
  const float* Wg   = (const float*)d_in[4];
  const float* Wgk  = (const float*)d_in[5];
  const float* bgk  = (const float*)d_in[6];
  const float* Wo   = (const float*)d_in[7];
  const float* gw   = (const float*)d_in[8];

  float* ws = (float*)d_ws;
  size_t off = 0;
  float* gk = ws + off; off += (size_t)16 * N_;
  float* gc = ws + off; off += (size_t)16 * N_;
  float* q  = ws + off; off += (size_t)M_ * 1024;
  float* k  = ws + off; off += (size_t)M_ * 1024;
  ushort_t* v16 = (ushort_t*)(ws + off); off += (size_t)M_ * 2048 / 2;
  ushort_t* o   = (ushort_t*)(ws + off); off += (size_t)M_ * 2048 / 2;
  ushort_t* ab16= (ushort_t*)(ws + off); off += (size_t)16 * NC_ * 4096 / 2;
  ushort_t* q16 = (ushort_t*)(ws + off); off += (size_t)M_ * 1024 / 2;
  ushort_t* kTp = (ushort_t*)(ws + off); off += (size_t)16 * NC_ * 16384 / 2;
  ushort_t* vTp = (ushort_t*)(ws + off); off += (size_t)16 * 512 * 2048 / 2;
  ushort_t* xb  = (ushort_t*)(ws + off); off += (size_t)M_ * HID_ / 2;
  ushort_t* WqT = (ushort_t*)(ws + off); off += (size_t)1024 * 1024 / 2;
  ushort_t* WkT = (ushort_t*)(ws + off); off += (size_t)1024 * 1024 / 2;
  ushort_t* WvT = (ushort_t*)(ws + off); off += (size_t)2048 * 1024 / 2;
  ushort_t* WgT = (ushort_t*)(ws + off); off += (size_t)2048 * 1024 / 2;
  ushort_t* WoT = (ushort_t*)(ws + off); off += (size_t)1024 * 2048 / 2;
  float*    g   = q;                 // 16M fl over q+k (dead after packs)
  ushort_t* ob  = q16;               // 8.39M fl over q16+kT (dead after scan)

  dim3 thr(256);
  conv_to_bf16<<<M_ * HID_ / 1024, thr, 0, stream>>>(x, xb);
  transp_bf16<<<dim3(32, 32), thr, 0, stream>>>(Wq, WqT, 1024, 1024);
  transp_bf16<<<dim3(32, 32), thr, 0, stream>>>(Wk, WkT, 1024, 1024);
  transp_bf16<<<dim3(64, 32), thr, 0, stream>>>(Wv, WvT, 1024, 2048);
  transp_bf16<<<dim3(64, 32), thr, 0, stream>>>(Wg, WgT, 1024, 2048);
  transp_bf16<<<dim3(32, 64), thr, 0, stream>>>(Wo, WoT, 2048, 1024);

  gemm_mfma<false><<<dim3(8, 64), thr, 0, stream>>>(xb, WqT, q, 1024, 1024);
  gemm_mfma<false><<<dim3(8, 64), thr, 0, stream>>>(xb, WkT, k, 1024, 1024);
  gk_kernel<<<M_, thr, 0, stream>>>(x, Wgk, bgk, gk);
  cumsum_kernel<<<16, 64, 0, stream>>>(gk, gc);
  a_kernel<<<16 * NC_, thr, 0, stream>>>(q, k, gc, ab16);
  pack_q16<<<M_ * 1024 / 1024, thr, 0, stream>>>(q, gc, q16);
  pack_kT<<<16 * NC_, thr, 0, stream>>>(k, gc, kTp);
  gemm_mfma<true><<<dim3(16, 64), thr, 0, stream>>>(xb, WvT, v16, 2048, 1024);
  pack_vT<<<16 * NC_ * 2, thr, 0, stream>>>(v16, vTp);
  scan_mfma<<<dim3(16, 16), thr, 0, stream>>>(q16, kTp, vTp, ab16, gc, o);
  gemm_mfma<false><<<dim3(16, 64), thr, 0, stream>>>(xb, WgT, g, 2048, 1024);
  normgate_kernel<<<M_ * NH_, thr, 0, stream>>>(o, g, gw, ob);
  gemm_mfma<false><<<dim3(8, 64), thr, 0, stream>>>(ob, WoT, (float*)d_out, 1024, 2048);
}